// Round 1
// baseline (59.861 us; speedup 1.0000x reference)
//
#include <hip/hip_runtime.h>
#include <float.h>

// ROI max-pooling, matching the JAX reference:
//   h0=(int)(H*r0); h1=(int)(H*r2); step=(h1-h0)/7
//   bin i<6: [h0+i*step, h0+(i+1)*step); bin 6: [h0+6*step, h1)
//   step==0 -> all valid pixels land in bin 6; empty bin -> -FLT_MAX
constexpr int H = 64, W = 64, C = 256, PH = 7, PW = 7;

__global__ __launch_bounds__(64) void roi_pool_kernel(
    const float* __restrict__ fm, const float* __restrict__ rois,
    float* __restrict__ out, int B, int R)
{
    int bid = blockIdx.x;
    int j = bid % PW; bid /= PW;
    int i = bid % PH; bid /= PH;
    int r = bid % R;
    int b = bid / R;

    const float* roi = rois + ((size_t)b * R + r) * 4;
    int h0 = (int)((float)H * roi[0]);   // truncation == astype(int32), inputs >= 0
    int w0 = (int)((float)W * roi[1]);
    int h1 = (int)((float)H * roi[2]);
    int w1 = (int)((float)W * roi[3]);
    int hs = (h1 - h0) / PH;
    int ws = (w1 - w0) / PW;

    int ys, ye, xs, xe;
    if (hs > 0) { ys = h0 + i * hs; ye = (i < PH - 1) ? (ys + hs) : h1; }
    else        { ys = h0;          ye = (i == PH - 1) ? h1 : h0; }   // i<6 empty
    if (ws > 0) { xs = w0 + j * ws; xe = (j < PW - 1) ? (xs + ws) : w1; }
    else        { xs = w0;          xe = (j == PW - 1) ? w1 : w0; }
    ys = max(ys, 0); ye = min(ye, H);
    xs = max(xs, 0); xe = min(xe, W);

    const int t = threadIdx.x;           // lane 0..63 -> channels 4t..4t+3
    float4 acc = make_float4(-FLT_MAX, -FLT_MAX, -FLT_MAX, -FLT_MAX);
    const float* fmb = fm + (size_t)b * H * W * C + t * 4;
    for (int y = ys; y < ye; ++y) {
        const float* row = fmb + (size_t)y * W * C;
        for (int x = xs; x < xe; ++x) {
            const float4 v = *reinterpret_cast<const float4*>(row + (size_t)x * C);
            acc.x = fmaxf(acc.x, v.x);
            acc.y = fmaxf(acc.y, v.y);
            acc.z = fmaxf(acc.z, v.z);
            acc.w = fmaxf(acc.w, v.w);
        }
    }
    size_t o = ((((size_t)b * R + r) * PH + i) * PW + j) * C + (size_t)t * 4;
    *reinterpret_cast<float4*>(out + o) = acc;
}

extern "C" void kernel_launch(void* const* d_in, const int* in_sizes, int n_in,
                              void* d_out, int out_size, void* d_ws, size_t ws_size,
                              hipStream_t stream) {
    const float* fm   = (const float*)d_in[0];
    const float* rois = (const float*)d_in[1];
    float* out = (float*)d_out;

    const int B = in_sizes[0] / (H * W * C);        // = 2
    const int R = in_sizes[1] / (B * 4);            // = 256

    const int nblocks = B * R * PH * PW;            // 25088 waves
    roi_pool_kernel<<<nblocks, 64, 0, stream>>>(fm, rois, out, B, R);
}